// Round 5
// baseline (318.617 us; speedup 1.0000x reference)
//
#include <hip/hip_runtime.h>
#include <hip/hip_bf16.h>

// GTO_Atten pipeline V5, MI355X (gfx950).
// V4 + attn2 occupancy fix: 16 queries/wave, pws -> 33.8KB (4 blocks/CU),
// launch_bounds(256,4). Everything else unchanged from passing V4.

#define NB 4
#define NSEQ 8192
#define CD 512
#define NH 8
#define TD 64
#define NTOK 256
#define NSPLIT 16
#define NKEYS (NSEQ / NSPLIT)   // 512 keys per split

typedef unsigned short u16;
typedef __bf16 bf16x8 __attribute__((ext_vector_type(8)));
typedef float f32x4 __attribute__((ext_vector_type(4)));

__device__ __forceinline__ u16 f2bf(float f){
  __hip_bfloat16 h = __float2bfloat16(f);
  u16 u; __builtin_memcpy(&u, &h, 2); return u;
}
__device__ __forceinline__ bf16x8 ld8(const u16* p){
  bf16x8 r; __builtin_memcpy(&r, p, 16); return r;
}
__device__ __forceinline__ f32x4 mfma16(bf16x8 a, bf16x8 b, f32x4 c){
  return __builtin_amdgcn_mfma_f32_16x16x32_bf16(a, b, c, 0, 0, 0);
}

// ---------------- K-1: W0 fp32 -> bf16 (flat copy) ----------------------------------
__global__ void k_cvt(const float* __restrict__ W0, u16* __restrict__ W0b){
  size_t i = (size_t)blockIdx.x * 256 + threadIdx.x;   // one float4 each; grid exact
  float4 v = ((const float4*)W0)[i];
  u16 w[4] = { f2bf(v.x), f2bf(v.y), f2bf(v.z), f2bf(v.w) };
  __builtin_memcpy(W0b + i*4, w, 8);
}

// ---------------- K0: prep (weights -> bf16 transposed [n][k]; Q,q3_w pre-scaled) ----
__global__ void k_prep(const float* __restrict__ kv1_w, const float* __restrict__ q3_w,
                       const float* __restrict__ proj_w, const float* __restrict__ Q,
                       u16* __restrict__ kv1_wt, u16* __restrict__ q3_wt,
                       u16* __restrict__ proj_wt, u16* __restrict__ Qb){
  int i = blockIdx.x * 256 + threadIdx.x;   // grid exact: CD*CD
  int k = i >> 9, n = i & 511;
  kv1_wt [n*CD + k] = f2bf(kv1_w[i]);
  q3_wt  [n*CD + k] = f2bf(q3_w[i] * 0.125f);   // fold 1/sqrt(td)
  proj_wt[n*CD + k] = f2bf(proj_w[i]);
  if (i < NH*NTOK*TD) Qb[i] = f2bf(Q[i] * 0.125f); // fold 1/sqrt(td)
}

// ---------------- GEMM: C[M][512] = A[M][512] @ B + bias; A bf16, Bt is [n][k] bf16 --
template<int OUT_F32>
__global__ __launch_bounds__(256, 2)
void k_gemm512(const u16* __restrict__ A, const u16* __restrict__ Bt,
               const float* __restrict__ bias, float bscale, void* __restrict__ outp){
  __shared__ __attribute__((aligned(16))) u16 As[128][72];
  __shared__ __attribute__((aligned(16))) u16 Bs[128][72];
  const int tid = threadIdx.x;
  const int lane = tid & 63, wave = tid >> 6;
  const int l15 = lane & 15, lg = lane >> 4;
  const int wm = (wave >> 1) * 64, wn = (wave & 1) * 64;
  const int bm = blockIdx.x, bn = blockIdx.y;
  f32x4 acc[4][4] = {};

#pragma unroll 1
  for (int k0 = 0; k0 < CD; k0 += 64){
    __syncthreads();
    {
      int r0 = tid >> 3, c8 = (tid & 7) << 3;
#pragma unroll
      for (int rr = 0; rr < 128; rr += 32){
        const u16* srcA = A  + (size_t)(bm*128 + r0 + rr) * CD + k0 + c8;
        int4 va = *(const int4*)srcA;
        __builtin_memcpy(&As[r0 + rr][c8], &va, 16);
        const u16* srcB = Bt + (size_t)(bn*128 + r0 + rr) * CD + k0 + c8;
        int4 vb = *(const int4*)srcB;
        __builtin_memcpy(&Bs[r0 + rr][c8], &vb, 16);
      }
    }
    __syncthreads();
#pragma unroll
    for (int ks = 0; ks < 2; ks++){
      bf16x8 af[4], bfr[4];
#pragma unroll
      for (int mf = 0; mf < 4; mf++) af[mf]  = ld8(&As[wm + mf*16 + l15][ks*32 + lg*8]);
#pragma unroll
      for (int nf = 0; nf < 4; nf++) bfr[nf] = ld8(&Bs[wn + nf*16 + l15][ks*32 + lg*8]);
#pragma unroll
      for (int mf = 0; mf < 4; mf++)
#pragma unroll
        for (int nf = 0; nf < 4; nf++)
          acc[mf][nf] = mfma16(af[mf], bfr[nf], acc[mf][nf]);
    }
  }
#pragma unroll
  for (int nf = 0; nf < 4; nf++){
    int col = bn*128 + wn + nf*16 + l15;
    float bv = bias[col] * bscale;
#pragma unroll
    for (int mf = 0; mf < 4; mf++){
      int row = bm*128 + wm + mf*16 + lg*4;
#pragma unroll
      for (int q = 0; q < 4; q++){
        float v = acc[mf][nf][q] + bv;
        if constexpr (OUT_F32) ((float*)outp)[(size_t)(row + q)*CD + col] = v;
        else                   ((u16*)outp)[(size_t)(row + q)*CD + col] = f2bf(v);
      }
    }
  }
}

// ---------------- K2: attn1 partial flash (m-split x n-split) -----------------------
__global__ __launch_bounds__(256, 4)
void k_attn1(const u16* __restrict__ kv1, const u16* __restrict__ Qb,
             float* __restrict__ o_part, float* __restrict__ ml_part){
  __shared__ __attribute__((aligned(16))) u16 kvs[64][72];    // [n][td]
  __shared__ __attribute__((aligned(16))) u16 kvts[64][72];   // [td][n]
  __shared__ __attribute__((aligned(16))) u16 pws[4][32][72]; // per-wave P [m][n]
  const int tid = threadIdx.x, lane = tid & 63, wave = tid >> 6;
  const int bh = blockIdx.x, mt = blockIdx.y, s = blockIdx.z;
  const int b = bh >> 3, h = bh & 7;
  const int l15 = lane & 15, lg = lane >> 4;
  const int m0 = mt*128 + wave*32;

  bf16x8 qf[2][2];
#pragma unroll
  for (int mf = 0; mf < 2; mf++)
#pragma unroll
    for (int ks = 0; ks < 2; ks++)
      qf[mf][ks] = ld8(Qb + (size_t)(h*NTOK + m0 + mf*16 + l15)*TD + ks*32 + lg*8);

  float mst[2][4], lst[2][4];
  f32x4 oac[2][4] = {};
#pragma unroll
  for (int mf = 0; mf < 2; mf++)
#pragma unroll
    for (int q = 0; q < 4; q++){ mst[mf][q] = -1e30f; lst[mf][q] = 0.f; }

#pragma unroll 1
  for (int c = 0; c < NKEYS/64; c++){
    const int nc = s*NKEYS + c*64;
    __syncthreads();
    {
      int r = tid >> 2, seg = (tid & 3) * 16;
      const u16* src = kv1 + (size_t)(b*NSEQ + nc + r)*CD + h*TD + seg;
      int4 v0 = *(const int4*)src;
      int4 v1 = *(const int4*)(src + 8);
      __builtin_memcpy(&kvs[r][seg],     &v0, 16);
      __builtin_memcpy(&kvs[r][seg + 8], &v1, 16);
      u16 tmp[16];
      __builtin_memcpy(tmp,     &v0, 16);
      __builtin_memcpy(tmp + 8, &v1, 16);
#pragma unroll
      for (int j = 0; j < 16; j++) kvts[seg + j][r] = tmp[j];
    }
    __syncthreads();
    f32x4 d[2][4] = {};
#pragma unroll
    for (int nf = 0; nf < 4; nf++)
#pragma unroll
      for (int ks = 0; ks < 2; ks++){
        bf16x8 kf = ld8(&kvs[nf*16 + l15][ks*32 + lg*8]);
#pragma unroll
        for (int mf = 0; mf < 2; mf++) d[mf][nf] = mfma16(qf[mf][ks], kf, d[mf][nf]);
      }
#pragma unroll
    for (int mf = 0; mf < 2; mf++)
#pragma unroll
      for (int q = 0; q < 4; q++){
        float cm = fmaxf(fmaxf(d[mf][0][q], d[mf][1][q]), fmaxf(d[mf][2][q], d[mf][3][q]));
#pragma unroll
        for (int off = 1; off < 16; off <<= 1) cm = fmaxf(cm, __shfl_xor(cm, off, 64));
        float mnew = fmaxf(mst[mf][q], cm);
        float corr = __expf(mst[mf][q] - mnew);
        float rs = 0.f;
#pragma unroll
        for (int nf = 0; nf < 4; nf++){
          float e = __expf(d[mf][nf][q] - mnew);
          d[mf][nf][q] = e; rs += e;
        }
#pragma unroll
        for (int off = 1; off < 16; off <<= 1) rs += __shfl_xor(rs, off, 64);
        lst[mf][q] = lst[mf][q]*corr + rs;
        mst[mf][q] = mnew;
#pragma unroll
        for (int tf = 0; tf < 4; tf++) oac[mf][tf][q] *= corr;
        int ml = mf*16 + lg*4 + q;
#pragma unroll
        for (int nf = 0; nf < 4; nf++) pws[wave][ml][nf*16 + l15] = f2bf(d[mf][nf][q]);
      }
#pragma unroll
    for (int ks = 0; ks < 2; ks++){
      bf16x8 a[2];
#pragma unroll
      for (int mf = 0; mf < 2; mf++) a[mf] = ld8(&pws[wave][mf*16 + l15][ks*32 + lg*8]);
#pragma unroll
      for (int tf = 0; tf < 4; tf++){
        bf16x8 vf = ld8(&kvts[tf*16 + l15][ks*32 + lg*8]);
#pragma unroll
        for (int mf = 0; mf < 2; mf++) oac[mf][tf] = mfma16(a[mf], vf, oac[mf][tf]);
      }
    }
  }
  const size_t pbase = (size_t)(bh*NSPLIT + s);
#pragma unroll
  for (int mf = 0; mf < 2; mf++)
#pragma unroll
    for (int q = 0; q < 4; q++){
      int m = m0 + mf*16 + lg*4 + q;
#pragma unroll
      for (int tf = 0; tf < 4; tf++)
        o_part[(pbase*NTOK + m)*TD + tf*16 + l15] = oac[mf][tf][q];
      if (l15 == 0){
        ml_part[(pbase*2)*NTOK + m]     = mst[mf][q];
        ml_part[(pbase*2 + 1)*NTOK + m] = lst[mf][q];
      }
    }
}

// ---------------- K3: combine partials + kv2 GEMM -----------------------------------
__global__ __launch_bounds__(256, 2)
void k_comb(const float* __restrict__ o_part, const float* __restrict__ ml_part,
            const float* __restrict__ qkv2_w, u16* __restrict__ kb, u16* __restrict__ vtb){
  __shared__ float w2[TD*2*TD];       // 32KB
  __shared__ float osh[16][68];
  const int tid = threadIdx.x;
  const int bh = blockIdx.x >> 4, mtile = blockIdx.x & 15;
  const int m0 = mtile * 16;
  for (int i = tid; i < TD*2*TD/4; i += 256) ((float4*)w2)[i] = ((const float4*)qkv2_w)[i];

  const int mi = tid >> 4, tj = tid & 15;
  const int m = m0 + mi;
  float M = -1e30f;
#pragma unroll
  for (int s = 0; s < NSPLIT; s++)
    M = fmaxf(M, ml_part[(size_t)((bh*NSPLIT + s)*2)*NTOK + m]);
  float4 acc = make_float4(0.f,0.f,0.f,0.f);
  float denom = 0.f;
#pragma unroll 1
  for (int s = 0; s < NSPLIT; s++){
    size_t base = (size_t)(bh*NSPLIT + s);
    float w = __expf(ml_part[(base*2)*NTOK + m] - M);
    denom += ml_part[(base*2 + 1)*NTOK + m] * w;
    float4 v = ((const float4*)(o_part + (base*NTOK + m)*TD))[tj];
    acc.x += w*v.x; acc.y += w*v.y; acc.z += w*v.z; acc.w += w*v.w;
  }
  float inv = 1.f / denom;
  osh[mi][tj*4+0] = acc.x*inv; osh[mi][tj*4+1] = acc.y*inv;
  osh[mi][tj*4+2] = acc.z*inv; osh[mi][tj*4+3] = acc.w*inv;
  __syncthreads();
  const int j0 = tj * 8;
  float o8[8] = {};
#pragma unroll
  for (int t = 0; t < TD; t++){
    float ov = osh[mi][t];
#pragma unroll
    for (int jj = 0; jj < 8; jj++) o8[jj] += ov * w2[t*2*TD + j0 + jj];
  }
  if (j0 < TD){
#pragma unroll
    for (int jj = 0; jj < 8; jj++)
      kb[(size_t)(bh*NTOK + m)*TD + j0 + jj] = f2bf(o8[jj]);
  } else {
#pragma unroll
    for (int jj = 0; jj < 8; jj++)
      vtb[(size_t)(bh*TD + (j0 - TD + jj))*NTOK + m] = f2bf(o8[jj]);
  }
}

// ---------------- K5: attn2 V5 — 16 queries/wave, single-pass softmax ---------------
// Full 256-key logit row in regs (d[16] f32x4 = 64 VGPR); pws 33.8KB -> 4 blocks/CU.
__global__ __launch_bounds__(256, 4)
void k_attn2(const u16* __restrict__ q3, const u16* __restrict__ kb,
             const u16* __restrict__ vtb, u16* __restrict__ Wout){
  __shared__ __attribute__((aligned(16))) u16 pws[4][16][264];  // 33792 B
  const int tid = threadIdx.x, lane = tid & 63, wave = tid >> 6;
  const int bh = blockIdx.x >> 7, nt = blockIdx.x & 127;
  const int b = bh >> 3, h = bh & 7;
  const int l15 = lane & 15, lg = lane >> 4;
  const int n0 = nt * 64 + wave * 16;

  // A-frags of q3 (pre-scaled by 1/8 in GEMM): rows n0..n0+15
  bf16x8 qf[2];
#pragma unroll
  for (int ks = 0; ks < 2; ks++)
    qf[ks] = ld8(q3 + (size_t)(b*NSEQ + n0 + l15)*CD + h*TD + ks*32 + lg*8);

  // QK^T: all 256 keys, logits stay in registers
  f32x4 d[16] = {};
#pragma unroll
  for (int nf = 0; nf < 16; nf++){
    const u16* kp = kb + (size_t)(bh*NTOK + nf*16 + l15)*TD + lg*8;
    bf16x8 b0 = ld8(kp);
    bf16x8 b1 = ld8(kp + 32);
    d[nf] = mfma16(qf[0], b0, d[nf]);
    d[nf] = mfma16(qf[1], b1, d[nf]);
  }

  // single-pass softmax per row (row = lg*4 + q; keys = nf*16 + l15)
  float rsum[4];
#pragma unroll
  for (int q = 0; q < 4; q++){
    float m = d[0][q];
#pragma unroll
    for (int nf = 1; nf < 16; nf++) m = fmaxf(m, d[nf][q]);
#pragma unroll
    for (int off = 1; off < 16; off <<= 1) m = fmaxf(m, __shfl_xor(m, off, 64));
    float rs = 0.f;
#pragma unroll
    for (int nf = 0; nf < 16; nf++){
      float e = __expf(d[nf][q] - m);
      d[nf][q] = e; rs += e;
    }
#pragma unroll
    for (int off = 1; off < 16; off <<= 1) rs += __shfl_xor(rs, off, 64);
    rsum[q] = rs;
    int rl = lg*4 + q;
#pragma unroll
    for (int nf = 0; nf < 16; nf++) pws[wave][rl][nf*16 + l15] = f2bf(d[nf][q]);
  }

  // PV: O[16 q][64 td] = P (LDS A-frags) x V (vtb [td][key] B-frags), sum over 256 keys
  f32x4 oac[4] = {};
#pragma unroll
  for (int ks = 0; ks < 8; ks++){
    bf16x8 a = ld8(&pws[wave][l15][ks*32 + lg*8]);
#pragma unroll
    for (int tf = 0; tf < 4; tf++){
      bf16x8 vf = ld8(vtb + (size_t)(bh*TD + tf*16 + l15)*NTOK + ks*32 + lg*8);
      oac[tf] = mfma16(a, vf, oac[tf]);
    }
  }

#pragma unroll
  for (int q = 0; q < 4; q++){
    float inv = 1.f / rsum[q];
    size_t row = (size_t)(b*NSEQ + n0 + lg*4 + q);
#pragma unroll
    for (int tf = 0; tf < 4; tf++)
      Wout[row*CD + h*TD + tf*16 + l15] = f2bf(oac[tf][q] * inv);
  }
}

// ---------------- host ----------------
extern "C" void kernel_launch(void* const* d_in, const int* in_sizes, int n_in,
                              void* d_out, int out_size, void* d_ws, size_t ws_size,
                              hipStream_t stream){
  const float* W0     = (const float*)d_in[0];
  const float* Q      = (const float*)d_in[1];
  const float* kv1_w  = (const float*)d_in[2];
  const float* kv1_b  = (const float*)d_in[3];
  const float* qkv2_w = (const float*)d_in[4];
  const float* q3_w   = (const float*)d_in[5];
  const float* q3_b   = (const float*)d_in[6];
  const float* proj_w = (const float*)d_in[7];
  const float* proj_b = (const float*)d_in[8];
  (void)in_sizes; (void)n_in; (void)out_size; (void)ws_size;

  char* ws = (char*)d_ws;
  u16*   W0b     = (u16*)  (ws);                                  // [0,32MiB)
  u16*   kv1_ws  = (u16*)  (ws + ((size_t)32<<20));               // [32,64) -> later W_ws
  float* o_part  = (float*)(ws + ((size_t)64<<20));               // [64,96) -> later q3_ws
  float* ml_part = (float*)(ws + ((size_t)96<<20));               // [96,97)
  u16*   kv1_wt  = (u16*)  (ws + ((size_t)97<<20));               // 512 KiB
  u16*   q3_wt   = (u16*)  (ws + ((size_t)97<<20) + (1<<19));     // 512 KiB
  u16*   proj_wt = (u16*)  (ws + ((size_t)98<<20));               // 512 KiB
  u16*   Qb      = (u16*)  (ws + ((size_t)98<<20) + (1<<19));     // 256 KiB
  u16*   kb      = (u16*)  (ws + ((size_t)99<<20));               // 1 MiB
  u16*   vtb     = (u16*)  (ws + ((size_t)100<<20));              // 1 MiB; total ~101 MiB
  u16*   q3_ws   = (u16*)  (ws + ((size_t)64<<20));               // alias o_part
  u16*   W_ws    = (u16*)  (ws + ((size_t)32<<20));               // alias kv1_ws

  k_cvt<<<16384, 256, 0, stream>>>(W0, W0b);
  k_prep<<<1024, 256, 0, stream>>>(kv1_w, q3_w, proj_w, Q, kv1_wt, q3_wt, proj_wt, Qb);
  k_gemm512<0><<<dim3(256,4), 256, 0, stream>>>(W0b, kv1_wt, kv1_b, 1.0f, (void*)kv1_ws);
  k_attn1<<<dim3(NB*NH, 2, NSPLIT), 256, 0, stream>>>(kv1_ws, Qb, o_part, ml_part);
  k_comb<<<NB*NH*16, 256, 0, stream>>>(o_part, ml_part, qkv2_w, kb, vtb);
  k_gemm512<0><<<dim3(256,4), 256, 0, stream>>>(W0b, q3_wt, q3_b, 0.125f, (void*)q3_ws);
  k_attn2<<<NB*NH*128, 256, 0, stream>>>(q3_ws, kb, vtb, W_ws);
  k_gemm512<1><<<dim3(256,4), 256, 0, stream>>>(W_ws, proj_wt, proj_b, 1.0f, (void*)d_out);
}

// Round 6
// 252.191 us; speedup vs baseline: 1.2634x; 1.2634x over previous
//
#include <hip/hip_runtime.h>
#include <hip/hip_bf16.h>

// GTO_Atten pipeline V6, MI355X (gfx950).
// V4-attn2 (proven 89.6us) + fused dual-GEMM (kv1+q3 share one A staging).
// q3 bf16 output lives in first 32MB of d_out (fp32 64MB), dead before proj writes.

#define NB 4
#define NSEQ 8192
#define CD 512
#define NH 8
#define TD 64
#define NTOK 256
#define NSPLIT 16
#define NKEYS (NSEQ / NSPLIT)   // 512 keys per split

typedef unsigned short u16;
typedef __bf16 bf16x8 __attribute__((ext_vector_type(8)));
typedef float f32x4 __attribute__((ext_vector_type(4)));

__device__ __forceinline__ u16 f2bf(float f){
  __hip_bfloat16 h = __float2bfloat16(f);
  u16 u; __builtin_memcpy(&u, &h, 2); return u;
}
__device__ __forceinline__ bf16x8 ld8(const u16* p){
  bf16x8 r; __builtin_memcpy(&r, p, 16); return r;
}
__device__ __forceinline__ f32x4 mfma16(bf16x8 a, bf16x8 b, f32x4 c){
  return __builtin_amdgcn_mfma_f32_16x16x32_bf16(a, b, c, 0, 0, 0);
}

// ---------------- K-1: W0 fp32 -> bf16 (flat copy) ----------------------------------
__global__ void k_cvt(const float* __restrict__ W0, u16* __restrict__ W0b){
  size_t i = (size_t)blockIdx.x * 256 + threadIdx.x;   // one float4 each; grid exact
  float4 v = ((const float4*)W0)[i];
  u16 w[4] = { f2bf(v.x), f2bf(v.y), f2bf(v.z), f2bf(v.w) };
  __builtin_memcpy(W0b + i*4, w, 8);
}

// ---------------- K0: prep (weights -> bf16 transposed [n][k]; Q,q3_w pre-scaled) ----
__global__ void k_prep(const float* __restrict__ kv1_w, const float* __restrict__ q3_w,
                       const float* __restrict__ proj_w, const float* __restrict__ Q,
                       u16* __restrict__ kv1_wt, u16* __restrict__ q3_wt,
                       u16* __restrict__ proj_wt, u16* __restrict__ Qb){
  int i = blockIdx.x * 256 + threadIdx.x;   // grid exact: CD*CD
  int k = i >> 9, n = i & 511;
  kv1_wt [n*CD + k] = f2bf(kv1_w[i]);
  q3_wt  [n*CD + k] = f2bf(q3_w[i] * 0.125f);   // fold 1/sqrt(td)
  proj_wt[n*CD + k] = f2bf(proj_w[i]);
  if (i < NH*NTOK*TD) Qb[i] = f2bf(Q[i] * 0.125f); // fold 1/sqrt(td)
}

// ---------------- Fused dual GEMM: A(32768x512) x {B1,B2} -> two bf16 outputs -------
__global__ __launch_bounds__(256, 2)
void k_gemm_dual(const u16* __restrict__ A, const u16* __restrict__ B1t,
                 const u16* __restrict__ B2t, const float* __restrict__ bias1,
                 const float* __restrict__ bias2, float bscale2,
                 u16* __restrict__ out1, u16* __restrict__ out2){
  __shared__ __attribute__((aligned(16))) u16 As[128][72];
  __shared__ __attribute__((aligned(16))) u16 B1s[128][72];
  __shared__ __attribute__((aligned(16))) u16 B2s[128][72];
  const int tid = threadIdx.x;
  const int lane = tid & 63, wave = tid >> 6;
  const int l15 = lane & 15, lg = lane >> 4;
  const int wm = (wave >> 1) * 64, wn = (wave & 1) * 64;
  const int bm = blockIdx.x, bn = blockIdx.y;
  f32x4 acc1[4][4] = {}, acc2[4][4] = {};

#pragma unroll 1
  for (int k0 = 0; k0 < CD; k0 += 64){
    __syncthreads();
    {
      int r0 = tid >> 3, c8 = (tid & 7) << 3;
#pragma unroll
      for (int rr = 0; rr < 128; rr += 32){
        const u16* srcA = A   + (size_t)(bm*128 + r0 + rr) * CD + k0 + c8;
        int4 va = *(const int4*)srcA;
        __builtin_memcpy(&As[r0 + rr][c8], &va, 16);
        const u16* s1 = B1t + (size_t)(bn*128 + r0 + rr) * CD + k0 + c8;
        int4 v1 = *(const int4*)s1;
        __builtin_memcpy(&B1s[r0 + rr][c8], &v1, 16);
        const u16* s2 = B2t + (size_t)(bn*128 + r0 + rr) * CD + k0 + c8;
        int4 v2 = *(const int4*)s2;
        __builtin_memcpy(&B2s[r0 + rr][c8], &v2, 16);
      }
    }
    __syncthreads();
#pragma unroll
    for (int ks = 0; ks < 2; ks++){
      bf16x8 af[4], b1f[4], b2f[4];
#pragma unroll
      for (int mf = 0; mf < 4; mf++) af[mf]  = ld8(&As[wm + mf*16 + l15][ks*32 + lg*8]);
#pragma unroll
      for (int nf = 0; nf < 4; nf++){
        b1f[nf] = ld8(&B1s[wn + nf*16 + l15][ks*32 + lg*8]);
        b2f[nf] = ld8(&B2s[wn + nf*16 + l15][ks*32 + lg*8]);
      }
#pragma unroll
      for (int mf = 0; mf < 4; mf++)
#pragma unroll
        for (int nf = 0; nf < 4; nf++){
          acc1[mf][nf] = mfma16(af[mf], b1f[nf], acc1[mf][nf]);
          acc2[mf][nf] = mfma16(af[mf], b2f[nf], acc2[mf][nf]);
        }
    }
  }
#pragma unroll
  for (int nf = 0; nf < 4; nf++){
    int col = bn*128 + wn + nf*16 + l15;
    float bv1 = bias1[col];
    float bv2 = bias2[col] * bscale2;
#pragma unroll
    for (int mf = 0; mf < 4; mf++){
      int row = bm*128 + wm + mf*16 + lg*4;
#pragma unroll
      for (int q = 0; q < 4; q++){
        out1[(size_t)(row + q)*CD + col] = f2bf(acc1[mf][nf][q] + bv1);
        out2[(size_t)(row + q)*CD + col] = f2bf(acc2[mf][nf][q] + bv2);
      }
    }
  }
}

// ---------------- GEMM: C[M][512] = A[M][512] @ B + bias (proj) ---------------------
template<int OUT_F32>
__global__ __launch_bounds__(256, 2)
void k_gemm512(const u16* __restrict__ A, const u16* __restrict__ Bt,
               const float* __restrict__ bias, float bscale, void* __restrict__ outp){
  __shared__ __attribute__((aligned(16))) u16 As[128][72];
  __shared__ __attribute__((aligned(16))) u16 Bs[128][72];
  const int tid = threadIdx.x;
  const int lane = tid & 63, wave = tid >> 6;
  const int l15 = lane & 15, lg = lane >> 4;
  const int wm = (wave >> 1) * 64, wn = (wave & 1) * 64;
  const int bm = blockIdx.x, bn = blockIdx.y;
  f32x4 acc[4][4] = {};

#pragma unroll 1
  for (int k0 = 0; k0 < CD; k0 += 64){
    __syncthreads();
    {
      int r0 = tid >> 3, c8 = (tid & 7) << 3;
#pragma unroll
      for (int rr = 0; rr < 128; rr += 32){
        const u16* srcA = A  + (size_t)(bm*128 + r0 + rr) * CD + k0 + c8;
        int4 va = *(const int4*)srcA;
        __builtin_memcpy(&As[r0 + rr][c8], &va, 16);
        const u16* srcB = Bt + (size_t)(bn*128 + r0 + rr) * CD + k0 + c8;
        int4 vb = *(const int4*)srcB;
        __builtin_memcpy(&Bs[r0 + rr][c8], &vb, 16);
      }
    }
    __syncthreads();
#pragma unroll
    for (int ks = 0; ks < 2; ks++){
      bf16x8 af[4], bfr[4];
#pragma unroll
      for (int mf = 0; mf < 4; mf++) af[mf]  = ld8(&As[wm + mf*16 + l15][ks*32 + lg*8]);
#pragma unroll
      for (int nf = 0; nf < 4; nf++) bfr[nf] = ld8(&Bs[wn + nf*16 + l15][ks*32 + lg*8]);
#pragma unroll
      for (int mf = 0; mf < 4; mf++)
#pragma unroll
        for (int nf = 0; nf < 4; nf++)
          acc[mf][nf] = mfma16(af[mf], bfr[nf], acc[mf][nf]);
    }
  }
#pragma unroll
  for (int nf = 0; nf < 4; nf++){
    int col = bn*128 + wn + nf*16 + l15;
    float bv = bias[col] * bscale;
#pragma unroll
    for (int mf = 0; mf < 4; mf++){
      int row = bm*128 + wm + mf*16 + lg*4;
#pragma unroll
      for (int q = 0; q < 4; q++){
        float v = acc[mf][nf][q] + bv;
        if constexpr (OUT_F32) ((float*)outp)[(size_t)(row + q)*CD + col] = v;
        else                   ((u16*)outp)[(size_t)(row + q)*CD + col] = f2bf(v);
      }
    }
  }
}

// ---------------- K2: attn1 partial flash (m-split x n-split) -----------------------
__global__ __launch_bounds__(256, 4)
void k_attn1(const u16* __restrict__ kv1, const u16* __restrict__ Qb,
             float* __restrict__ o_part, float* __restrict__ ml_part){
  __shared__ __attribute__((aligned(16))) u16 kvs[64][72];    // [n][td]
  __shared__ __attribute__((aligned(16))) u16 kvts[64][72];   // [td][n]
  __shared__ __attribute__((aligned(16))) u16 pws[4][32][72]; // per-wave P [m][n]
  const int tid = threadIdx.x, lane = tid & 63, wave = tid >> 6;
  const int bh = blockIdx.x, mt = blockIdx.y, s = blockIdx.z;
  const int b = bh >> 3, h = bh & 7;
  const int l15 = lane & 15, lg = lane >> 4;
  const int m0 = mt*128 + wave*32;

  bf16x8 qf[2][2];
#pragma unroll
  for (int mf = 0; mf < 2; mf++)
#pragma unroll
    for (int ks = 0; ks < 2; ks++)
      qf[mf][ks] = ld8(Qb + (size_t)(h*NTOK + m0 + mf*16 + l15)*TD + ks*32 + lg*8);

  float mst[2][4], lst[2][4];
  f32x4 oac[2][4] = {};
#pragma unroll
  for (int mf = 0; mf < 2; mf++)
#pragma unroll
    for (int q = 0; q < 4; q++){ mst[mf][q] = -1e30f; lst[mf][q] = 0.f; }

#pragma unroll 1
  for (int c = 0; c < NKEYS/64; c++){
    const int nc = s*NKEYS + c*64;
    __syncthreads();
    {
      int r = tid >> 2, seg = (tid & 3) * 16;
      const u16* src = kv1 + (size_t)(b*NSEQ + nc + r)*CD + h*TD + seg;
      int4 v0 = *(const int4*)src;
      int4 v1 = *(const int4*)(src + 8);
      __builtin_memcpy(&kvs[r][seg],     &v0, 16);
      __builtin_memcpy(&kvs[r][seg + 8], &v1, 16);
      u16 tmp[16];
      __builtin_memcpy(tmp,     &v0, 16);
      __builtin_memcpy(tmp + 8, &v1, 16);
#pragma unroll
      for (int j = 0; j < 16; j++) kvts[seg + j][r] = tmp[j];
    }
    __syncthreads();
    f32x4 d[2][4] = {};
#pragma unroll
    for (int nf = 0; nf < 4; nf++)
#pragma unroll
      for (int ks = 0; ks < 2; ks++){
        bf16x8 kf = ld8(&kvs[nf*16 + l15][ks*32 + lg*8]);
#pragma unroll
        for (int mf = 0; mf < 2; mf++) d[mf][nf] = mfma16(qf[mf][ks], kf, d[mf][nf]);
      }
#pragma unroll
    for (int mf = 0; mf < 2; mf++)
#pragma unroll
      for (int q = 0; q < 4; q++){
        float cm = fmaxf(fmaxf(d[mf][0][q], d[mf][1][q]), fmaxf(d[mf][2][q], d[mf][3][q]));
#pragma unroll
        for (int off = 1; off < 16; off <<= 1) cm = fmaxf(cm, __shfl_xor(cm, off, 64));
        float mnew = fmaxf(mst[mf][q], cm);
        float corr = __expf(mst[mf][q] - mnew);
        float rs = 0.f;
#pragma unroll
        for (int nf = 0; nf < 4; nf++){
          float e = __expf(d[mf][nf][q] - mnew);
          d[mf][nf][q] = e; rs += e;
        }
#pragma unroll
        for (int off = 1; off < 16; off <<= 1) rs += __shfl_xor(rs, off, 64);
        lst[mf][q] = lst[mf][q]*corr + rs;
        mst[mf][q] = mnew;
#pragma unroll
        for (int tf = 0; tf < 4; tf++) oac[mf][tf][q] *= corr;
        int ml = mf*16 + lg*4 + q;
#pragma unroll
        for (int nf = 0; nf < 4; nf++) pws[wave][ml][nf*16 + l15] = f2bf(d[mf][nf][q]);
      }
#pragma unroll
    for (int ks = 0; ks < 2; ks++){
      bf16x8 a[2];
#pragma unroll
      for (int mf = 0; mf < 2; mf++) a[mf] = ld8(&pws[wave][mf*16 + l15][ks*32 + lg*8]);
#pragma unroll
      for (int tf = 0; tf < 4; tf++){
        bf16x8 vf = ld8(&kvts[tf*16 + l15][ks*32 + lg*8]);
#pragma unroll
        for (int mf = 0; mf < 2; mf++) oac[mf][tf] = mfma16(a[mf], vf, oac[mf][tf]);
      }
    }
  }
  const size_t pbase = (size_t)(bh*NSPLIT + s);
#pragma unroll
  for (int mf = 0; mf < 2; mf++)
#pragma unroll
    for (int q = 0; q < 4; q++){
      int m = m0 + mf*16 + lg*4 + q;
#pragma unroll
      for (int tf = 0; tf < 4; tf++)
        o_part[(pbase*NTOK + m)*TD + tf*16 + l15] = oac[mf][tf][q];
      if (l15 == 0){
        ml_part[(pbase*2)*NTOK + m]     = mst[mf][q];
        ml_part[(pbase*2 + 1)*NTOK + m] = lst[mf][q];
      }
    }
}

// ---------------- K3: combine partials + kv2 GEMM -----------------------------------
__global__ __launch_bounds__(256, 2)
void k_comb(const float* __restrict__ o_part, const float* __restrict__ ml_part,
            const float* __restrict__ qkv2_w, u16* __restrict__ kb, u16* __restrict__ vtb){
  __shared__ float w2[TD*2*TD];       // 32KB
  __shared__ float osh[16][68];
  const int tid = threadIdx.x;
  const int bh = blockIdx.x >> 4, mtile = blockIdx.x & 15;
  const int m0 = mtile * 16;
  for (int i = tid; i < TD*2*TD/4; i += 256) ((float4*)w2)[i] = ((const float4*)qkv2_w)[i];

  const int mi = tid >> 4, tj = tid & 15;
  const int m = m0 + mi;
  float M = -1e30f;
#pragma unroll
  for (int s = 0; s < NSPLIT; s++)
    M = fmaxf(M, ml_part[(size_t)((bh*NSPLIT + s)*2)*NTOK + m]);
  float4 acc = make_float4(0.f,0.f,0.f,0.f);
  float denom = 0.f;
#pragma unroll 1
  for (int s = 0; s < NSPLIT; s++){
    size_t base = (size_t)(bh*NSPLIT + s);
    float w = __expf(ml_part[(base*2)*NTOK + m] - M);
    denom += ml_part[(base*2 + 1)*NTOK + m] * w;
    float4 v = ((const float4*)(o_part + (base*NTOK + m)*TD))[tj];
    acc.x += w*v.x; acc.y += w*v.y; acc.z += w*v.z; acc.w += w*v.w;
  }
  float inv = 1.f / denom;
  osh[mi][tj*4+0] = acc.x*inv; osh[mi][tj*4+1] = acc.y*inv;
  osh[mi][tj*4+2] = acc.z*inv; osh[mi][tj*4+3] = acc.w*inv;
  __syncthreads();
  const int j0 = tj * 8;
  float o8[8] = {};
#pragma unroll
  for (int t = 0; t < TD; t++){
    float ov = osh[mi][t];
#pragma unroll
    for (int jj = 0; jj < 8; jj++) o8[jj] += ov * w2[t*2*TD + j0 + jj];
  }
  if (j0 < TD){
#pragma unroll
    for (int jj = 0; jj < 8; jj++)
      kb[(size_t)(bh*NTOK + m)*TD + j0 + jj] = f2bf(o8[jj]);
  } else {
#pragma unroll
    for (int jj = 0; jj < 8; jj++)
      vtb[(size_t)(bh*TD + (j0 - TD + jj))*NTOK + m] = f2bf(o8[jj]);
  }
}

// ---------------- K5: attn2 (V4 proven): 32 q/wave, single-pass softmax -------------
__global__ __launch_bounds__(256, 2)
void k_attn2(const u16* __restrict__ q3, const u16* __restrict__ kb,
             const u16* __restrict__ vtb, u16* __restrict__ Wout){
  __shared__ __attribute__((aligned(16))) u16 pws[4][32][264];  // 66KB
  const int tid = threadIdx.x, lane = tid & 63, wave = tid >> 6;
  const int bh = blockIdx.x >> 6, nt = blockIdx.x & 63;
  const int b = bh >> 3, h = bh & 7;
  const int l15 = lane & 15, lg = lane >> 4;
  const int n0 = nt * 128 + wave * 32;

  bf16x8 qf[2][2];
#pragma unroll
  for (int mf = 0; mf < 2; mf++)
#pragma unroll
    for (int ks = 0; ks < 2; ks++)
      qf[mf][ks] = ld8(q3 + (size_t)(b*NSEQ + n0 + mf*16 + l15)*CD + h*TD + ks*32 + lg*8);

  f32x4 d[2][16] = {};
#pragma unroll
  for (int nf = 0; nf < 16; nf++){
    const u16* kp = kb + (size_t)(bh*NTOK + nf*16 + l15)*TD + lg*8;
    bf16x8 b0 = ld8(kp);
    bf16x8 b1 = ld8(kp + 32);
    d[0][nf] = mfma16(qf[0][0], b0, d[0][nf]);
    d[0][nf] = mfma16(qf[0][1], b1, d[0][nf]);
    d[1][nf] = mfma16(qf[1][0], b0, d[1][nf]);
    d[1][nf] = mfma16(qf[1][1], b1, d[1][nf]);
  }

  float rsum[2][4];
#pragma unroll
  for (int mf = 0; mf < 2; mf++)
#pragma unroll
    for (int q = 0; q < 4; q++){
      float m = d[mf][0][q];
#pragma unroll
      for (int nf = 1; nf < 16; nf++) m = fmaxf(m, d[mf][nf][q]);
#pragma unroll
      for (int off = 1; off < 16; off <<= 1) m = fmaxf(m, __shfl_xor(m, off, 64));
      float rs = 0.f;
#pragma unroll
      for (int nf = 0; nf < 16; nf++){
        float e = __expf(d[mf][nf][q] - m);
        d[mf][nf][q] = e; rs += e;
      }
#pragma unroll
      for (int off = 1; off < 16; off <<= 1) rs += __shfl_xor(rs, off, 64);
      rsum[mf][q] = rs;
      int rl = mf*16 + lg*4 + q;
#pragma unroll
      for (int nf = 0; nf < 16; nf++) pws[wave][rl][nf*16 + l15] = f2bf(d[mf][nf][q]);
    }

  f32x4 oac[2][4] = {};
#pragma unroll
  for (int ks = 0; ks < 8; ks++){
    bf16x8 a0 = ld8(&pws[wave][l15][ks*32 + lg*8]);
    bf16x8 a1 = ld8(&pws[wave][16 + l15][ks*32 + lg*8]);
#pragma unroll
    for (int tf = 0; tf < 4; tf++){
      bf16x8 vf = ld8(vtb + (size_t)(bh*TD + tf*16 + l15)*NTOK + ks*32 + lg*8);
      oac[0][tf] = mfma16(a0, vf, oac[0][tf]);
      oac[1][tf] = mfma16(a1, vf, oac[1][tf]);
    }
  }

#pragma unroll
  for (int mf = 0; mf < 2; mf++)
#pragma unroll
    for (int q = 0; q < 4; q++){
      float inv = 1.f / rsum[mf][q];
      size_t row = (size_t)(b*NSEQ + n0 + mf*16 + lg*4 + q);
#pragma unroll
      for (int tf = 0; tf < 4; tf++)
        Wout[row*CD + h*TD + tf*16 + l15] = f2bf(oac[mf][tf][q] * inv);
    }
}

// ---------------- host ----------------
extern "C" void kernel_launch(void* const* d_in, const int* in_sizes, int n_in,
                              void* d_out, int out_size, void* d_ws, size_t ws_size,
                              hipStream_t stream){
  const float* W0     = (const float*)d_in[0];
  const float* Q      = (const float*)d_in[1];
  const float* kv1_w  = (const float*)d_in[2];
  const float* kv1_b  = (const float*)d_in[3];
  const float* qkv2_w = (const float*)d_in[4];
  const float* q3_w   = (const float*)d_in[5];
  const float* q3_b   = (const float*)d_in[6];
  const float* proj_w = (const float*)d_in[7];
  const float* proj_b = (const float*)d_in[8];
  (void)in_sizes; (void)n_in; (void)out_size; (void)ws_size;

  char* ws = (char*)d_ws;
  u16*   W0b     = (u16*)  (ws);                                  // [0,32MiB)
  u16*   kv1_ws  = (u16*)  (ws + ((size_t)32<<20));               // [32,64) -> later W_ws
  float* o_part  = (float*)(ws + ((size_t)64<<20));               // [64,96)
  float* ml_part = (float*)(ws + ((size_t)96<<20));               // [96,97)
  u16*   kv1_wt  = (u16*)  (ws + ((size_t)97<<20));               // 512 KiB
  u16*   q3_wt   = (u16*)  (ws + ((size_t)97<<20) + (1<<19));     // 512 KiB
  u16*   proj_wt = (u16*)  (ws + ((size_t)98<<20));               // 512 KiB
  u16*   Qb      = (u16*)  (ws + ((size_t)98<<20) + (1<<19));     // 256 KiB
  u16*   kb      = (u16*)  (ws + ((size_t)99<<20));               // 1 MiB
  u16*   vtb     = (u16*)  (ws + ((size_t)100<<20));              // 1 MiB; total ~101 MiB
  u16*   W_ws    = (u16*)  (ws + ((size_t)32<<20));               // alias kv1_ws
  u16*   q3s     = (u16*)  d_out;                                 // first 32MB of d_out (64MB f32)

  k_cvt<<<16384, 256, 0, stream>>>(W0, W0b);
  k_prep<<<1024, 256, 0, stream>>>(kv1_w, q3_w, proj_w, Q, kv1_wt, q3_wt, proj_wt, Qb);
  k_gemm_dual<<<dim3(256,4), 256, 0, stream>>>(W0b, kv1_wt, q3_wt, kv1_b, q3_b, 0.125f,
                                               kv1_ws, q3s);
  k_attn1<<<dim3(NB*NH, 2, NSPLIT), 256, 0, stream>>>(kv1_ws, Qb, o_part, ml_part);
  k_comb<<<NB*NH*16, 256, 0, stream>>>(o_part, ml_part, qkv2_w, kb, vtb);
  k_attn2<<<NB*NH*64, 256, 0, stream>>>(q3s, kb, vtb, W_ws);
  k_gemm512<1><<<dim3(256,4), 256, 0, stream>>>(W_ws, proj_wt, proj_b, 1.0f, (void*)d_out);
}

// Round 7
// 249.938 us; speedup vs baseline: 1.2748x; 1.0090x over previous
//
#include <hip/hip_runtime.h>
#include <hip/hip_bf16.h>

// GTO_Atten pipeline V7, MI355X (gfx950).
// V6 + attn2 rewritten on swapped-QK^T 32x32 MFMA (m214 recipe): in-register
// softmax (2 cross-lane ops), in-register P->PV repack, no P LDS staging.

#define NB 4
#define NSEQ 8192
#define CD 512
#define NH 8
#define TD 64
#define NTOK 256
#define NSPLIT 16
#define NKEYS (NSEQ / NSPLIT)   // 512 keys per split

typedef unsigned short u16;
typedef unsigned int u32;
typedef __bf16 bf16x8 __attribute__((ext_vector_type(8)));
typedef float f32x4 __attribute__((ext_vector_type(4)));
typedef float f32x16 __attribute__((ext_vector_type(16)));

__device__ __forceinline__ u16 f2bf(float f){
  __hip_bfloat16 h = __float2bfloat16(f);
  u16 u; __builtin_memcpy(&u, &h, 2); return u;
}
__device__ __forceinline__ bf16x8 ld8(const u16* p){
  bf16x8 r; __builtin_memcpy(&r, p, 16); return r;
}
__device__ __forceinline__ f32x4 mfma16(bf16x8 a, bf16x8 b, f32x4 c){
  return __builtin_amdgcn_mfma_f32_16x16x32_bf16(a, b, c, 0, 0, 0);
}
__device__ __forceinline__ f32x16 mfma32(bf16x8 a, bf16x8 b, f32x16 c){
  return __builtin_amdgcn_mfma_f32_32x32x16_bf16(a, b, c, 0, 0, 0);
}

// ---------------- K-1: W0 fp32 -> bf16 (flat copy) ----------------------------------
__global__ void k_cvt(const float* __restrict__ W0, u16* __restrict__ W0b){
  size_t i = (size_t)blockIdx.x * 256 + threadIdx.x;   // one float4 each; grid exact
  float4 v = ((const float4*)W0)[i];
  u16 w[4] = { f2bf(v.x), f2bf(v.y), f2bf(v.z), f2bf(v.w) };
  __builtin_memcpy(W0b + i*4, w, 8);
}

// ---------------- K0: prep (weights -> bf16 transposed [n][k]; Q,q3_w pre-scaled) ----
__global__ void k_prep(const float* __restrict__ kv1_w, const float* __restrict__ q3_w,
                       const float* __restrict__ proj_w, const float* __restrict__ Q,
                       u16* __restrict__ kv1_wt, u16* __restrict__ q3_wt,
                       u16* __restrict__ proj_wt, u16* __restrict__ Qb){
  int i = blockIdx.x * 256 + threadIdx.x;   // grid exact: CD*CD
  int k = i >> 9, n = i & 511;
  kv1_wt [n*CD + k] = f2bf(kv1_w[i]);
  q3_wt  [n*CD + k] = f2bf(q3_w[i] * 0.125f);   // fold 1/sqrt(td)
  proj_wt[n*CD + k] = f2bf(proj_w[i]);
  if (i < NH*NTOK*TD) Qb[i] = f2bf(Q[i] * 0.125f); // fold 1/sqrt(td)
}

// ---------------- Fused dual GEMM: A(32768x512) x {B1,B2} -> two bf16 outputs -------
__global__ __launch_bounds__(256, 2)
void k_gemm_dual(const u16* __restrict__ A, const u16* __restrict__ B1t,
                 const u16* __restrict__ B2t, const float* __restrict__ bias1,
                 const float* __restrict__ bias2, float bscale2,
                 u16* __restrict__ out1, u16* __restrict__ out2){
  __shared__ __attribute__((aligned(16))) u16 As[128][72];
  __shared__ __attribute__((aligned(16))) u16 B1s[128][72];
  __shared__ __attribute__((aligned(16))) u16 B2s[128][72];
  const int tid = threadIdx.x;
  const int lane = tid & 63, wave = tid >> 6;
  const int l15 = lane & 15, lg = lane >> 4;
  const int wm = (wave >> 1) * 64, wn = (wave & 1) * 64;
  const int bm = blockIdx.x, bn = blockIdx.y;
  f32x4 acc1[4][4] = {}, acc2[4][4] = {};

#pragma unroll 1
  for (int k0 = 0; k0 < CD; k0 += 64){
    __syncthreads();
    {
      int r0 = tid >> 3, c8 = (tid & 7) << 3;
#pragma unroll
      for (int rr = 0; rr < 128; rr += 32){
        const u16* srcA = A   + (size_t)(bm*128 + r0 + rr) * CD + k0 + c8;
        int4 va = *(const int4*)srcA;
        __builtin_memcpy(&As[r0 + rr][c8], &va, 16);
        const u16* s1 = B1t + (size_t)(bn*128 + r0 + rr) * CD + k0 + c8;
        int4 v1 = *(const int4*)s1;
        __builtin_memcpy(&B1s[r0 + rr][c8], &v1, 16);
        const u16* s2 = B2t + (size_t)(bn*128 + r0 + rr) * CD + k0 + c8;
        int4 v2 = *(const int4*)s2;
        __builtin_memcpy(&B2s[r0 + rr][c8], &v2, 16);
      }
    }
    __syncthreads();
#pragma unroll
    for (int ks = 0; ks < 2; ks++){
      bf16x8 af[4], b1f[4], b2f[4];
#pragma unroll
      for (int mf = 0; mf < 4; mf++) af[mf]  = ld8(&As[wm + mf*16 + l15][ks*32 + lg*8]);
#pragma unroll
      for (int nf = 0; nf < 4; nf++){
        b1f[nf] = ld8(&B1s[wn + nf*16 + l15][ks*32 + lg*8]);
        b2f[nf] = ld8(&B2s[wn + nf*16 + l15][ks*32 + lg*8]);
      }
#pragma unroll
      for (int mf = 0; mf < 4; mf++)
#pragma unroll
        for (int nf = 0; nf < 4; nf++){
          acc1[mf][nf] = mfma16(af[mf], b1f[nf], acc1[mf][nf]);
          acc2[mf][nf] = mfma16(af[mf], b2f[nf], acc2[mf][nf]);
        }
    }
  }
#pragma unroll
  for (int nf = 0; nf < 4; nf++){
    int col = bn*128 + wn + nf*16 + l15;
    float bv1 = bias1[col];
    float bv2 = bias2[col] * bscale2;
#pragma unroll
    for (int mf = 0; mf < 4; mf++){
      int row = bm*128 + wm + mf*16 + lg*4;
#pragma unroll
      for (int q = 0; q < 4; q++){
        out1[(size_t)(row + q)*CD + col] = f2bf(acc1[mf][nf][q] + bv1);
        out2[(size_t)(row + q)*CD + col] = f2bf(acc2[mf][nf][q] + bv2);
      }
    }
  }
}

// ---------------- GEMM: C[M][512] = A[M][512] @ B + bias (proj) ---------------------
template<int OUT_F32>
__global__ __launch_bounds__(256, 2)
void k_gemm512(const u16* __restrict__ A, const u16* __restrict__ Bt,
               const float* __restrict__ bias, float bscale, void* __restrict__ outp){
  __shared__ __attribute__((aligned(16))) u16 As[128][72];
  __shared__ __attribute__((aligned(16))) u16 Bs[128][72];
  const int tid = threadIdx.x;
  const int lane = tid & 63, wave = tid >> 6;
  const int l15 = lane & 15, lg = lane >> 4;
  const int wm = (wave >> 1) * 64, wn = (wave & 1) * 64;
  const int bm = blockIdx.x, bn = blockIdx.y;
  f32x4 acc[4][4] = {};

#pragma unroll 1
  for (int k0 = 0; k0 < CD; k0 += 64){
    __syncthreads();
    {
      int r0 = tid >> 3, c8 = (tid & 7) << 3;
#pragma unroll
      for (int rr = 0; rr < 128; rr += 32){
        const u16* srcA = A  + (size_t)(bm*128 + r0 + rr) * CD + k0 + c8;
        int4 va = *(const int4*)srcA;
        __builtin_memcpy(&As[r0 + rr][c8], &va, 16);
        const u16* srcB = Bt + (size_t)(bn*128 + r0 + rr) * CD + k0 + c8;
        int4 vb = *(const int4*)srcB;
        __builtin_memcpy(&Bs[r0 + rr][c8], &vb, 16);
      }
    }
    __syncthreads();
#pragma unroll
    for (int ks = 0; ks < 2; ks++){
      bf16x8 af[4], bfr[4];
#pragma unroll
      for (int mf = 0; mf < 4; mf++) af[mf]  = ld8(&As[wm + mf*16 + l15][ks*32 + lg*8]);
#pragma unroll
      for (int nf = 0; nf < 4; nf++) bfr[nf] = ld8(&Bs[wn + nf*16 + l15][ks*32 + lg*8]);
#pragma unroll
      for (int mf = 0; mf < 4; mf++)
#pragma unroll
        for (int nf = 0; nf < 4; nf++)
          acc[mf][nf] = mfma16(af[mf], bfr[nf], acc[mf][nf]);
    }
  }
#pragma unroll
  for (int nf = 0; nf < 4; nf++){
    int col = bn*128 + wn + nf*16 + l15;
    float bv = bias[col] * bscale;
#pragma unroll
    for (int mf = 0; mf < 4; mf++){
      int row = bm*128 + wm + mf*16 + lg*4;
#pragma unroll
      for (int q = 0; q < 4; q++){
        float v = acc[mf][nf][q] + bv;
        if constexpr (OUT_F32) ((float*)outp)[(size_t)(row + q)*CD + col] = v;
        else                   ((u16*)outp)[(size_t)(row + q)*CD + col] = f2bf(v);
      }
    }
  }
}

// ---------------- K2: attn1 partial flash (m-split x n-split) -----------------------
__global__ __launch_bounds__(256, 4)
void k_attn1(const u16* __restrict__ kv1, const u16* __restrict__ Qb,
             float* __restrict__ o_part, float* __restrict__ ml_part){
  __shared__ __attribute__((aligned(16))) u16 kvs[64][72];    // [n][td]
  __shared__ __attribute__((aligned(16))) u16 kvts[64][72];   // [td][n]
  __shared__ __attribute__((aligned(16))) u16 pws[4][32][72]; // per-wave P [m][n]
  const int tid = threadIdx.x, lane = tid & 63, wave = tid >> 6;
  const int bh = blockIdx.x, mt = blockIdx.y, s = blockIdx.z;
  const int b = bh >> 3, h = bh & 7;
  const int l15 = lane & 15, lg = lane >> 4;
  const int m0 = mt*128 + wave*32;

  bf16x8 qf[2][2];
#pragma unroll
  for (int mf = 0; mf < 2; mf++)
#pragma unroll
    for (int ks = 0; ks < 2; ks++)
      qf[mf][ks] = ld8(Qb + (size_t)(h*NTOK + m0 + mf*16 + l15)*TD + ks*32 + lg*8);

  float mst[2][4], lst[2][4];
  f32x4 oac[2][4] = {};
#pragma unroll
  for (int mf = 0; mf < 2; mf++)
#pragma unroll
    for (int q = 0; q < 4; q++){ mst[mf][q] = -1e30f; lst[mf][q] = 0.f; }

#pragma unroll 1
  for (int c = 0; c < NKEYS/64; c++){
    const int nc = s*NKEYS + c*64;
    __syncthreads();
    {
      int r = tid >> 2, seg = (tid & 3) * 16;
      const u16* src = kv1 + (size_t)(b*NSEQ + nc + r)*CD + h*TD + seg;
      int4 v0 = *(const int4*)src;
      int4 v1 = *(const int4*)(src + 8);
      __builtin_memcpy(&kvs[r][seg],     &v0, 16);
      __builtin_memcpy(&kvs[r][seg + 8], &v1, 16);
      u16 tmp[16];
      __builtin_memcpy(tmp,     &v0, 16);
      __builtin_memcpy(tmp + 8, &v1, 16);
#pragma unroll
      for (int j = 0; j < 16; j++) kvts[seg + j][r] = tmp[j];
    }
    __syncthreads();
    f32x4 d[2][4] = {};
#pragma unroll
    for (int nf = 0; nf < 4; nf++)
#pragma unroll
      for (int ks = 0; ks < 2; ks++){
        bf16x8 kf = ld8(&kvs[nf*16 + l15][ks*32 + lg*8]);
#pragma unroll
        for (int mf = 0; mf < 2; mf++) d[mf][nf] = mfma16(qf[mf][ks], kf, d[mf][nf]);
      }
#pragma unroll
    for (int mf = 0; mf < 2; mf++)
#pragma unroll
      for (int q = 0; q < 4; q++){
        float cm = fmaxf(fmaxf(d[mf][0][q], d[mf][1][q]), fmaxf(d[mf][2][q], d[mf][3][q]));
#pragma unroll
        for (int off = 1; off < 16; off <<= 1) cm = fmaxf(cm, __shfl_xor(cm, off, 64));
        float mnew = fmaxf(mst[mf][q], cm);
        float corr = __expf(mst[mf][q] - mnew);
        float rs = 0.f;
#pragma unroll
        for (int nf = 0; nf < 4; nf++){
          float e = __expf(d[mf][nf][q] - mnew);
          d[mf][nf][q] = e; rs += e;
        }
#pragma unroll
        for (int off = 1; off < 16; off <<= 1) rs += __shfl_xor(rs, off, 64);
        lst[mf][q] = lst[mf][q]*corr + rs;
        mst[mf][q] = mnew;
#pragma unroll
        for (int tf = 0; tf < 4; tf++) oac[mf][tf][q] *= corr;
        int ml = mf*16 + lg*4 + q;
#pragma unroll
        for (int nf = 0; nf < 4; nf++) pws[wave][ml][nf*16 + l15] = f2bf(d[mf][nf][q]);
      }
#pragma unroll
    for (int ks = 0; ks < 2; ks++){
      bf16x8 a[2];
#pragma unroll
      for (int mf = 0; mf < 2; mf++) a[mf] = ld8(&pws[wave][mf*16 + l15][ks*32 + lg*8]);
#pragma unroll
      for (int tf = 0; tf < 4; tf++){
        bf16x8 vf = ld8(&kvts[tf*16 + l15][ks*32 + lg*8]);
#pragma unroll
        for (int mf = 0; mf < 2; mf++) oac[mf][tf] = mfma16(a[mf], vf, oac[mf][tf]);
      }
    }
  }
  const size_t pbase = (size_t)(bh*NSPLIT + s);
#pragma unroll
  for (int mf = 0; mf < 2; mf++)
#pragma unroll
    for (int q = 0; q < 4; q++){
      int m = m0 + mf*16 + lg*4 + q;
#pragma unroll
      for (int tf = 0; tf < 4; tf++)
        o_part[(pbase*NTOK + m)*TD + tf*16 + l15] = oac[mf][tf][q];
      if (l15 == 0){
        ml_part[(pbase*2)*NTOK + m]     = mst[mf][q];
        ml_part[(pbase*2 + 1)*NTOK + m] = lst[mf][q];
      }
    }
}

// ---------------- K3: combine partials + kv2 GEMM -----------------------------------
__global__ __launch_bounds__(256, 2)
void k_comb(const float* __restrict__ o_part, const float* __restrict__ ml_part,
            const float* __restrict__ qkv2_w, u16* __restrict__ kb, u16* __restrict__ vtb){
  __shared__ float w2[TD*2*TD];       // 32KB
  __shared__ float osh[16][68];
  const int tid = threadIdx.x;
  const int bh = blockIdx.x >> 4, mtile = blockIdx.x & 15;
  const int m0 = mtile * 16;
  for (int i = tid; i < TD*2*TD/4; i += 256) ((float4*)w2)[i] = ((const float4*)qkv2_w)[i];

  const int mi = tid >> 4, tj = tid & 15;
  const int m = m0 + mi;
  float M = -1e30f;
#pragma unroll
  for (int s = 0; s < NSPLIT; s++)
    M = fmaxf(M, ml_part[(size_t)((bh*NSPLIT + s)*2)*NTOK + m]);
  float4 acc = make_float4(0.f,0.f,0.f,0.f);
  float denom = 0.f;
#pragma unroll 1
  for (int s = 0; s < NSPLIT; s++){
    size_t base = (size_t)(bh*NSPLIT + s);
    float w = __expf(ml_part[(base*2)*NTOK + m] - M);
    denom += ml_part[(base*2 + 1)*NTOK + m] * w;
    float4 v = ((const float4*)(o_part + (base*NTOK + m)*TD))[tj];
    acc.x += w*v.x; acc.y += w*v.y; acc.z += w*v.z; acc.w += w*v.w;
  }
  float inv = 1.f / denom;
  osh[mi][tj*4+0] = acc.x*inv; osh[mi][tj*4+1] = acc.y*inv;
  osh[mi][tj*4+2] = acc.z*inv; osh[mi][tj*4+3] = acc.w*inv;
  __syncthreads();
  const int j0 = tj * 8;
  float o8[8] = {};
#pragma unroll
  for (int t = 0; t < TD; t++){
    float ov = osh[mi][t];
#pragma unroll
    for (int jj = 0; jj < 8; jj++) o8[jj] += ov * w2[t*2*TD + j0 + jj];
  }
  if (j0 < TD){
#pragma unroll
    for (int jj = 0; jj < 8; jj++)
      kb[(size_t)(bh*NTOK + m)*TD + j0 + jj] = f2bf(o8[jj]);
  } else {
#pragma unroll
    for (int jj = 0; jj < 8; jj++)
      vtb[(size_t)(bh*TD + (j0 - TD + jj))*NTOK + m] = f2bf(o8[jj]);
  }
}

// ---------------- K5: attn2 V7 — swapped-QK^T 32x32, in-register softmax ------------
// Per wave: 32 queries. P[key][query]: query=lane&31, 128 keys in-register.
// Softmax: in-lane trees + one shfl_xor(32) each for max/sum. P->PV B-frags via
// bf16 pack + 8 shfl_xor(32)/tile + cndmask. PV: A=V^T (vtb), B=P. No P LDS.
__global__ __launch_bounds__(256, 2)
void k_attn2(const u16* __restrict__ q3, const u16* __restrict__ kb,
             const u16* __restrict__ vtb, u16* __restrict__ Wout){
  __shared__ u16 osh[4][32][68];       // 17.4 KB: per-wave O transpose
  const int tid = threadIdx.x, lane = tid & 63, wave = tid >> 6;
  const int bh = blockIdx.x >> 6, nt = blockIdx.x & 63;
  const int b = bh >> 3, h = bh & 7;
  const int l31 = lane & 31, hi = lane >> 5;
  const int n0 = nt * 128 + wave * 32;

  // Q B-frags: col=query=l31, k=td = ks*16 + hi*8 + e  (q3 pre-scaled by 1/8)
  bf16x8 bq[4];
#pragma unroll
  for (int ks = 0; ks < 4; ks++)
    bq[ks] = ld8(q3 + (size_t)(b*NSEQ + n0 + l31)*CD + h*TD + ks*16 + hi*8);

  // QK^T swapped: p[kt] holds P[key=crow(r,hi)+kt*32][query=l31]
  f32x16 p[8] = {};
#pragma unroll
  for (int kt = 0; kt < 8; kt++){
#pragma unroll
    for (int ks = 0; ks < 4; ks++){
      bf16x8 ak = ld8(kb + (size_t)(bh*NTOK + kt*32 + l31)*TD + ks*16 + hi*8);
      p[kt] = mfma32(ak, bq[ks], p[kt]);
    }
  }

  // softmax over 256 keys of query l31 (other 128 keys live in lane^32)
  float mx0 = -1e30f, mx1 = -1e30f, mx2 = -1e30f, mx3 = -1e30f;
#pragma unroll
  for (int kt = 0; kt < 8; kt++){
#pragma unroll
    for (int r = 0; r < 16; r += 4){
      mx0 = fmaxf(mx0, p[kt][r+0]); mx1 = fmaxf(mx1, p[kt][r+1]);
      mx2 = fmaxf(mx2, p[kt][r+2]); mx3 = fmaxf(mx3, p[kt][r+3]);
    }
  }
  float m = fmaxf(fmaxf(mx0, mx1), fmaxf(mx2, mx3));
  m = fmaxf(m, __shfl_xor(m, 32, 64));
  float s0 = 0.f, s1 = 0.f, s2 = 0.f, s3 = 0.f;
#pragma unroll
  for (int kt = 0; kt < 8; kt++){
#pragma unroll
    for (int r = 0; r < 16; r += 4){
      float e0 = __expf(p[kt][r+0] - m); p[kt][r+0] = e0; s0 += e0;
      float e1 = __expf(p[kt][r+1] - m); p[kt][r+1] = e1; s1 += e1;
      float e2 = __expf(p[kt][r+2] - m); p[kt][r+2] = e2; s2 += e2;
      float e3 = __expf(p[kt][r+3] - m); p[kt][r+3] = e3; s3 += e3;
    }
  }
  float rs = (s0 + s1) + (s2 + s3);
  rs += __shfl_xor(rs, 32, 64);
  const float inv = 1.f / rs;

  // PV: O^T[td][query] = sum_keys V^T[td][key] * P[key][query]
  f32x16 o0 = {}, o1 = {};
#pragma unroll
  for (int kt = 0; kt < 8; kt++){
    u32 w[8], x[8];
#pragma unroll
    for (int j = 0; j < 8; j++){
      u32 lo = f2bf(p[kt][2*j]);
      u32 hh = f2bf(p[kt][2*j + 1]);
      w[j] = lo | (hh << 16);
    }
#pragma unroll
    for (int j = 0; j < 8; j++) x[j] = __shfl_xor(w[j], 32, 64);
#pragma unroll
    for (int c = 0; c < 2; c++){
      u32 arr[4];
      arr[0] = hi ? x[4*c + 2] : w[4*c + 0];
      arr[1] = hi ? x[4*c + 3] : w[4*c + 1];
      arr[2] = hi ? w[4*c + 2] : x[4*c + 0];
      arr[3] = hi ? w[4*c + 3] : x[4*c + 1];
      bf16x8 pb; __builtin_memcpy(&pb, arr, 16);
      const u16* vp = vtb + (size_t)(bh*TD + l31)*NTOK + kt*32 + c*16 + hi*8;
      bf16x8 av0 = ld8(vp);
      bf16x8 av1 = ld8(vp + (size_t)32*NTOK);
      o0 = mfma32(av0, pb, o0);
      o1 = mfma32(av1, pb, o1);
    }
  }

  // epilogue: O regs -> per-wave LDS transpose -> vectorized global stores
#pragma unroll
  for (int r = 0; r < 16; r++){
    int row = (r & 3) + 8*(r >> 2) + 4*hi;   // td within 32-block
    osh[wave][l31][row]      = f2bf(o0[r] * inv);
    osh[wave][l31][32 + row] = f2bf(o1[r] * inv);
  }
  // same-wave LDS read-back (lockstep; compiler inserts lgkmcnt)
  const u16* src = &osh[wave][l31][hi*32];
  int4 v0, v1;
  __builtin_memcpy(&v0, src,      16);
  __builtin_memcpy(&v1, src + 8,  16);
  int4 v2, v3;
  __builtin_memcpy(&v2, src + 16, 16);
  __builtin_memcpy(&v3, src + 24, 16);
  u16* dst = Wout + (size_t)(b*NSEQ + n0 + l31)*CD + h*TD + hi*32;
  __builtin_memcpy(dst,      &v0, 16);
  __builtin_memcpy(dst + 8,  &v1, 16);
  __builtin_memcpy(dst + 16, &v2, 16);
  __builtin_memcpy(dst + 24, &v3, 16);
}

// ---------------- host ----------------
extern "C" void kernel_launch(void* const* d_in, const int* in_sizes, int n_in,
                              void* d_out, int out_size, void* d_ws, size_t ws_size,
                              hipStream_t stream){
  const float* W0     = (const float*)d_in[0];
  const float* Q      = (const float*)d_in[1];
  const float* kv1_w  = (const float*)d_in[2];
  const float* kv1_b  = (const float*)d_in[3];
  const float* qkv2_w = (const float*)d_in[4];
  const float* q3_w   = (const float*)d_in[5];
  const float* q3_b   = (const float*)d_in[6];
  const float* proj_w = (const float*)d_in[7];
  const float* proj_b = (const float*)d_in[8];
  (void)in_sizes; (void)n_in; (void)out_size; (void)ws_size;

  char* ws = (char*)d_ws;
  u16*   W0b     = (u16*)  (ws);                                  // [0,32MiB)
  u16*   kv1_ws  = (u16*)  (ws + ((size_t)32<<20));               // [32,64) -> later W_ws
  float* o_part  = (float*)(ws + ((size_t)64<<20));               // [64,96)
  float* ml_part = (float*)(ws + ((size_t)96<<20));               // [96,97)
  u16*   kv1_wt  = (u16*)  (ws + ((size_t)97<<20));               // 512 KiB
  u16*   q3_wt   = (u16*)  (ws + ((size_t)97<<20) + (1<<19));     // 512 KiB
  u16*   proj_wt = (u16*)  (ws + ((size_t)98<<20));               // 512 KiB
  u16*   Qb      = (u16*)  (ws + ((size_t)98<<20) + (1<<19));     // 256 KiB
  u16*   kb      = (u16*)  (ws + ((size_t)99<<20));               // 1 MiB
  u16*   vtb     = (u16*)  (ws + ((size_t)100<<20));              // 1 MiB; total ~101 MiB
  u16*   W_ws    = (u16*)  (ws + ((size_t)32<<20));               // alias kv1_ws
  u16*   q3s     = (u16*)  d_out;                                 // first 32MB of d_out (64MB f32)

  k_cvt<<<16384, 256, 0, stream>>>(W0, W0b);
  k_prep<<<1024, 256, 0, stream>>>(kv1_w, q3_w, proj_w, Q, kv1_wt, q3_wt, proj_wt, Qb);
  k_gemm_dual<<<dim3(256,4), 256, 0, stream>>>(W0b, kv1_wt, q3_wt, kv1_b, q3_b, 0.125f,
                                               kv1_ws, q3s);
  k_attn1<<<dim3(NB*NH, 2, NSPLIT), 256, 0, stream>>>(kv1_ws, Qb, o_part, ml_part);
  k_comb<<<NB*NH*16, 256, 0, stream>>>(o_part, ml_part, qkv2_w, kb, vtb);
  k_attn2<<<NB*NH*64, 256, 0, stream>>>(q3s, kb, vtb, W_ws);
  k_gemm512<1><<<dim3(256,4), 256, 0, stream>>>(W_ws, proj_wt, proj_b, 1.0f, (void*)d_out);
}